// Round 5
// baseline (179.253 us; speedup 1.0000x reference)
//
#include <hip/hip_runtime.h>
#include <hip/hip_bf16.h>
#include <hip/hip_fp16.h>

typedef _Float16 half8 __attribute__((ext_vector_type(8)));
typedef _Float16 half4v __attribute__((ext_vector_type(4)));
typedef float float4v __attribute__((ext_vector_type(4)));

#define MFMA_F16(a, b, c) __builtin_amdgcn_mfma_f32_16x16x32_f16((a), (b), (c), 0, 0, 0)

// Async global->LDS DMA, 16B per lane. LDS dest = wave-uniform base + lane*16.
#define GLDS16(gp, lp) \
    __builtin_amdgcn_global_load_lds((const __attribute__((address_space(1))) unsigned int*)(gp), \
                                     (__attribute__((address_space(3))) unsigned int*)(lp), 16, 0, 0)

#define WAITCNT_VM(N) asm volatile("s_waitcnt vmcnt(" #N ")" ::: "memory")
#define SCHED_FENCE() __builtin_amdgcn_sched_barrier(0)
#define BARRIER() __builtin_amdgcn_s_barrier()

#define BATCH 8
#define SEQ   2048
#define DIM   1024
#define QD    128
#define BT    (BATCH * SEQ)          // 16384
#define NSPLIT 4
#define KSPAN (SEQ / NSPLIT)         // 512

// 16-lane all-lanes max reduction via DPP — pure VALU, stays off the LDS pipe.
__device__ __forceinline__ float dpp_max16(float x) {
    int v;
    v = __builtin_amdgcn_update_dpp(0, __float_as_int(x), 0xB1, 0xF, 0xF, false);  // quad_perm [1,0,3,2]
    x = fmaxf(x, __int_as_float(v));
    v = __builtin_amdgcn_update_dpp(0, __float_as_int(x), 0x4E, 0xF, 0xF, false);  // quad_perm [2,3,0,1]
    x = fmaxf(x, __int_as_float(v));
    v = __builtin_amdgcn_update_dpp(0, __float_as_int(x), 0x141, 0xF, 0xF, false); // row_half_mirror
    x = fmaxf(x, __int_as_float(v));
    v = __builtin_amdgcn_update_dpp(0, __float_as_int(x), 0x140, 0xF, 0xF, false); // row_mirror
    x = fmaxf(x, __int_as_float(v));
    return x;
}

// ---------------------------------------------------------------------------
// Weight convert (tiny, 768 KB total)
// ---------------------------------------------------------------------------
__global__ __launch_bounds__(256) void cvt_w_kernel(const float* __restrict__ Wq,
                                                    const float* __restrict__ Wk,
                                                    const float* __restrict__ Wv,
                                                    _Float16* __restrict__ Wh) {
    const float* src = (blockIdx.y == 0) ? Wq : ((blockIdx.y == 1) ? Wk : Wv);
    int i = blockIdx.x * 256 + threadIdx.x;
    float4 f = ((const float4*)src)[i];
    half4v h = {(_Float16)f.x, (_Float16)f.y, (_Float16)f.z, (_Float16)f.w};
    ((half4v*)(Wh + (size_t)blockIdx.y * QD * DIM))[i] = h;
}

// ---------------------------------------------------------------------------
// Projection v5: A (x) never touches LDS. The af fragment layout is
// lane=row, quad=8-contiguous-K — so each lane builds af straight from
// global f32 (16 rows x 128B coalesced segments per load), cvt in-register.
// Removes: A ds_write, A ds_read (32 of 128 b128/iter), As LDS.
// B (3 weight matrices) double-buffered via global_load_lds; counted
// vmcnt(8) BEFORE the barrier retires own W-DMAs (race-correct: post-barrier
// everyone's DMA is landed) while the 8 x-loads stay in flight.
// 512 threads, 8 waves = 2 row-halves x 4 col-quarters. LDS 96 KB, grid 256.
// ---------------------------------------------------------------------------
__global__ __launch_bounds__(512, 1) void proj_kernel(
    const float* __restrict__ x,         // (B*T, 1024) f32
    const _Float16* __restrict__ Wh,     // 3 x (128, 1024)
    _Float16* __restrict__ q_out,        // (B*T, 128)
    _Float16* __restrict__ k_out,        // (B*T, 128)
    _Float16* __restrict__ vt_out)       // (B, 128, T)
{
    __shared__ _Float16 Bs[2][3 * 128 * 64];     // 2 x 48 KB, swizzled

    const int tid  = threadIdx.x;
    const int lane = tid & 63;
    const int wave = tid >> 6;           // 0..7
    const int quad = lane >> 4;
    const int l15  = lane & 15;
    const int wr   = wave >> 2;          // 0..1 : 32-row half
    const int wcg  = wave & 3;           // 0..3 : 32-col quarter (per matrix)

    const int row0 = blockIdx.x * 64;

    // per-lane x base: row = row0 + wr*32 + rf*16 + l15 ; K = t*64 + kc*32 + quad*8
    const float* xr0 = x + (size_t)(row0 + wr * 32 + l15) * DIM + quad * 8;

    float4v acc[3][2][2];
#pragma unroll
    for (int m = 0; m < 3; m++)
#pragma unroll
        for (int rf = 0; rf < 2; rf++)
#pragma unroll
            for (int nf = 0; nf < 2; nf++)
                acc[m][rf][nf] = (float4v){0.f, 0.f, 0.f, 0.f};

    float4 ax[2][2][2];   // f32 prefetch regs for af, [rf][kc][lo/hi]

    // ---- prologue: D6(0) first, then af8(0) ----
#pragma unroll
    for (int c = 0; c < 6; c++) {
        int ci = c * 512 + tid;              // 0..3071
        int m  = ci >> 10;
        int ri = (ci >> 3) & 127;
        int g  = (ci & 7) ^ (ri & 7);
        GLDS16(Wh + (size_t)m * QD * DIM + (size_t)ri * DIM + g * 8, &Bs[0][ci * 8]);
    }
#pragma unroll
    for (int rf = 0; rf < 2; rf++)
#pragma unroll
        for (int kc = 0; kc < 2; kc++) {
            const float* p = xr0 + rf * 16 * DIM + kc * 32;
            ax[rf][kc][0] = *(const float4*)(p + 0);
            ax[rf][kc][1] = *(const float4*)(p + 4);
        }
    WAITCNT_VM(8);       // retire D6(0); keep the 8 x-loads in flight
    SCHED_FENCE();
    BARRIER();

#pragma unroll
    for (int t = 0; t < 16; t++) {
        const int cur = t & 1;
        const int nxt = cur ^ 1;

        // issue next W tile (FIFO: D6 before af8)
        if (t < 15) {
            const int kkn = (t + 1) * 64;
#pragma unroll
            for (int c = 0; c < 6; c++) {
                int ci = c * 512 + tid;
                int m  = ci >> 10;
                int ri = (ci >> 3) & 127;
                int g  = (ci & 7) ^ (ri & 7);
                GLDS16(Wh + (size_t)m * QD * DIM + (size_t)ri * DIM + kkn + g * 8,
                       &Bs[nxt][ci * 8]);
            }
        }

        // convert current af from prefetched f32 (compiler-waited)
        half8 af[2][2];
#pragma unroll
        for (int rf = 0; rf < 2; rf++)
#pragma unroll
            for (int kc = 0; kc < 2; kc++) {
                half8 h;
                h[0] = (_Float16)ax[rf][kc][0].x; h[1] = (_Float16)ax[rf][kc][0].y;
                h[2] = (_Float16)ax[rf][kc][0].z; h[3] = (_Float16)ax[rf][kc][0].w;
                h[4] = (_Float16)ax[rf][kc][1].x; h[5] = (_Float16)ax[rf][kc][1].y;
                h[6] = (_Float16)ax[rf][kc][1].z; h[7] = (_Float16)ax[rf][kc][1].w;
                af[rf][kc] = h;
            }

        // prefetch next x tile into ax (af8(t+1), after D6(t+1) in FIFO)
        if (t < 15) {
            const float* xk = xr0 + (t + 1) * 64;
#pragma unroll
            for (int rf = 0; rf < 2; rf++)
#pragma unroll
                for (int kc = 0; kc < 2; kc++) {
                    const float* p = xk + rf * 16 * DIM + kc * 32;
                    ax[rf][kc][0] = *(const float4*)(p + 0);
                    ax[rf][kc][1] = *(const float4*)(p + 4);
                }
        }

        // compute current tile from Bs[cur] (all waves' DMAs landed: post-barrier)
#pragma unroll
        for (int m = 0; m < 3; m++) {
            half8 bf[2][2];
#pragma unroll
            for (int nf = 0; nf < 2; nf++)
#pragma unroll
                for (int kc = 0; kc < 2; kc++) {
                    int r = wcg * 32 + nf * 16 + l15;
                    int g = (kc * 4 + quad) ^ (r & 7);
                    bf[nf][kc] = *(const half8*)&Bs[cur][m * 8192 + r * 64 + g * 8];
                }
#pragma unroll
            for (int kc = 0; kc < 2; kc++)
#pragma unroll
                for (int rf = 0; rf < 2; rf++)
#pragma unroll
                    for (int nf = 0; nf < 2; nf++)
                        acc[m][rf][nf] = MFMA_F16(af[rf][kc], bf[nf][kc], acc[m][rf][nf]);
        }

        // retire D6(t+1) BEFORE the barrier; af8(t+1) stays in flight
        if (t < 15) {
            asm volatile("s_waitcnt lgkmcnt(0)" ::: "memory");
            WAITCNT_VM(8);
            SCHED_FENCE();
            BARRIER();
        }
    }

    // Epilogue. C layout: col = l15, row = quad*4 + reg.
#pragma unroll
    for (int m = 0; m < 3; m++) {
        if (m == 2) {
#pragma unroll
            for (int rf = 0; rf < 2; rf++) {
                int grow0 = row0 + wr * 32 + rf * 16 + quad * 4;
                int b  = grow0 >> 11;
                int t0 = grow0 & 2047;
#pragma unroll
                for (int nf = 0; nf < 2; nf++) {
                    int col = wcg * 32 + nf * 16 + l15;
                    half4v h;
#pragma unroll
                    for (int r = 0; r < 4; r++) h[r] = (_Float16)acc[m][rf][nf][r];
                    *(half4v*)&vt_out[((size_t)(b * QD + col)) * SEQ + t0] = h;
                }
            }
        } else {
            _Float16* out = (m == 0) ? q_out : k_out;
#pragma unroll
            for (int rf = 0; rf < 2; rf++) {
                int grow0 = row0 + wr * 32 + rf * 16 + quad * 4;
#pragma unroll
                for (int nf = 0; nf < 2; nf++) {
                    int col = wcg * 32 + nf * 16 + l15;
#pragma unroll
                    for (int r = 0; r < 4; r++)
                        out[(size_t)(grow0 + r) * QD + col] = (_Float16)acc[m][rf][nf][r];
                }
            }
        }
    }
}

// ---------------------------------------------------------------------------
// Flash attention (round-3 form: __syncthreads staging, race-free).
// Block = 128 q-rows (4 waves x 32 rows), key blocks of 64, key-split over
// blockIdx.z. K/V staged via global_load_lds into XOR-swizzled LDS; P
// round-trip also swizzled. DPP row reductions; ones-column MFMA for l;
// fp16 unnormalized partials + (m,l) for merge. Mask as float bias {0,-1e30}.
// ---------------------------------------------------------------------------
__global__ __launch_bounds__(256, 2) void attn_kernel(
    const _Float16* __restrict__ q,    // (B*T, 128)
    const _Float16* __restrict__ k,    // (B*T, 128)
    const _Float16* __restrict__ vt,   // (B, 128, T)
    const int* __restrict__ mask,      // (B*T)
    _Float16* __restrict__ Op,         // (NSPLIT, B*T, 128)
    float2* __restrict__ ml)           // (NSPLIT, B*T)
{
    __shared__ _Float16 Ks[64 * 128];      // 16 KB swizzled: keys x 128d
    __shared__ _Float16 Vs[128 * 64];      // 16 KB swizzled: 128d x keys
    __shared__ _Float16 Ps[4 * 32 * 64];   // 16 KB swizzled, wave-private slabs
    __shared__ float Msf[64];

    const int tid  = threadIdx.x;
    const int lane = tid & 63;
    const int wave = tid >> 6;
    const int quad = lane >> 4;
    const int l15  = lane & 15;

    const int b  = blockIdx.y;
    const int z  = blockIdx.z;
    const int rowbase = blockIdx.x * 128 + wave * 32;

    half8 qf[2][4];
#pragma unroll
    for (int rf = 0; rf < 2; rf++) {
        const _Float16* qrow = q + ((size_t)(b * SEQ + rowbase + rf * 16 + l15)) * QD + quad * 8;
#pragma unroll
        for (int kc = 0; kc < 4; kc++)
            qf[rf][kc] = *(const half8*)(qrow + kc * 32);
    }

    const half8 onesv = {(_Float16)1, (_Float16)1, (_Float16)1, (_Float16)1,
                         (_Float16)1, (_Float16)1, (_Float16)1, (_Float16)1};

    float4v oacc[2][8];
#pragma unroll
    for (int rf = 0; rf < 2; rf++)
#pragma unroll
        for (int n = 0; n < 8; n++)
            oacc[rf][n] = (float4v){0.f, 0.f, 0.f, 0.f};
    float4v lacc[2] = {(float4v){0.f, 0.f, 0.f, 0.f}, (float4v){0.f, 0.f, 0.f, 0.f}};
    float mrow[2][4];
#pragma unroll
    for (int rf = 0; rf < 2; rf++)
#pragma unroll
        for (int r = 0; r < 4; r++) mrow[rf][r] = -1e30f;

    _Float16* Pw = &Ps[wave * 32 * 64];

    for (int sb = z * KSPAN; sb < z * KSPAN + KSPAN; sb += 64) {
        __syncthreads();
        // K: 64 keys x 128d = 1024 chunks; 4 DMA calls/wave, swizzled dest.
#pragma unroll
        for (int c = 0; c < 4; c++) {
            int ci = wave * 256 + c * 64 + lane;
            int r  = ci >> 4;                       // key
            int gs = ci & 15;
            int g  = (gs & 8) | ((gs ^ r) & 7);     // global group for this LDS slot
            GLDS16(k + ((size_t)(b * SEQ + sb + r)) * QD + g * 8, &Ks[(wave * 256 + c * 64) * 8]);
        }
        // V^T: 128d x 64 keys = 1024 chunks; 4 DMA calls/wave.
#pragma unroll
        for (int c = 0; c < 4; c++) {
            int ci = wave * 256 + c * 64 + lane;
            int r  = ci >> 3;                       // d
            int g  = ((ci & 7) ^ r) & 7;
            GLDS16(vt + ((size_t)(b * QD + r)) * SEQ + sb + g * 8, &Vs[(wave * 256 + c * 64) * 8]);
        }
        if (tid < 64) Msf[tid] = mask[b * SEQ + sb + tid] ? 0.f : -1e30f;
        __syncthreads();

        // S = Q K^T : 32 rows x 64 keys per wave, C layout
        float4v sacc[2][4];
#pragma unroll
        for (int rf = 0; rf < 2; rf++)
#pragma unroll
            for (int j = 0; j < 4; j++)
                sacc[rf][j] = (float4v){0.f, 0.f, 0.f, 0.f};
#pragma unroll
        for (int kc = 0; kc < 4; kc++) {
            half8 kf[4];
#pragma unroll
            for (int j = 0; j < 4; j++) {
                int r  = j * 16 + l15;
                int g  = kc * 4 + quad;
                int gs = (g & 8) | ((g ^ r) & 7);
                kf[j] = *(const half8*)&Ks[r * 128 + gs * 8];
            }
#pragma unroll
            for (int rf = 0; rf < 2; rf++)
#pragma unroll
                for (int j = 0; j < 4; j++)
                    sacc[rf][j] = MFMA_F16(qf[rf][kc], kf[j], sacc[rf][j]);
        }

        // mask-bias + row-max + online-softmax scale
        float alpha[2][4];
#pragma unroll
        for (int rf = 0; rf < 2; rf++) {
            float rmax[4] = {-1e30f, -1e30f, -1e30f, -1e30f};
#pragma unroll
            for (int j = 0; j < 4; j++) {
                float bias = Msf[j * 16 + l15];
#pragma unroll
                for (int r = 0; r < 4; r++) {
                    float s = sacc[rf][j][r] + bias;
                    sacc[rf][j][r] = s;
                    rmax[r] = fmaxf(rmax[r], s);
                }
            }
#pragma unroll
            for (int r = 0; r < 4; r++) {
                float rm = dpp_max16(rmax[r]);
                float mnew = fmaxf(mrow[rf][r], rm);
                alpha[rf][r] = __expf(mrow[rf][r] - mnew);
                mrow[rf][r] = mnew;
            }
        }

        // p = exp(s - m) -> wave-private swizzled LDS (C-layout write)
#pragma unroll
        for (int rf = 0; rf < 2; rf++)
#pragma unroll
            for (int j = 0; j < 4; j++) {
                int col = j * 16 + l15;
                int gc  = col >> 3;
#pragma unroll
                for (int r = 0; r < 4; r++) {
                    int m  = rf * 16 + quad * 4 + r;
                    int gs = (gc ^ m) & 7;
                    float p = __expf(sacc[rf][j][r] - mrow[rf][r]);
                    Pw[m * 64 + gs * 8 + (col & 7)] = (_Float16)p;
                }
            }

        // rescale accumulators
#pragma unroll
        for (int rf = 0; rf < 2; rf++) {
#pragma unroll
            for (int n = 0; n < 8; n++)
#pragma unroll
                for (int r = 0; r < 4; r++)
                    oacc[rf][n][r] *= alpha[rf][r];
#pragma unroll
            for (int r = 0; r < 4; r++) lacc[rf][r] *= alpha[rf][r];
        }

        // O += P V ; l += P 1
#pragma unroll
        for (int kc = 0; kc < 2; kc++) {
            half8 pf[2];
#pragma unroll
            for (int rf = 0; rf < 2; rf++) {
                int m  = rf * 16 + l15;
                int gs = ((kc * 4 + quad) ^ m) & 7;
                pf[rf] = *(const half8*)&Pw[m * 64 + gs * 8];
            }
#pragma unroll
            for (int n = 0; n < 8; n++) {
                int r  = n * 16 + l15;
                int gs = ((kc * 4 + quad) ^ r) & 7;
                half8 vf = *(const half8*)&Vs[r * 64 + gs * 8];
#pragma unroll
                for (int rf = 0; rf < 2; rf++)
                    oacc[rf][n] = MFMA_F16(pf[rf], vf, oacc[rf][n]);
            }
#pragma unroll
            for (int rf = 0; rf < 2; rf++)
                lacc[rf] = MFMA_F16(pf[rf], onesv, lacc[rf]);
        }
    }

    // Epilogue: fp16 unnormalized partials + (m, l)
    _Float16* Oz = Op + (size_t)z * BT * QD;
#pragma unroll
    for (int rf = 0; rf < 2; rf++) {
#pragma unroll
        for (int n = 0; n < 8; n++) {
            int col = n * 16 + l15;
#pragma unroll
            for (int r = 0; r < 4; r++) {
                int row = rowbase + rf * 16 + quad * 4 + r;
                Oz[((size_t)(b * SEQ + row)) * QD + col] = (_Float16)oacc[rf][n][r];
            }
        }
        if (l15 == 0) {
#pragma unroll
            for (int r = 0; r < 4; r++) {
                int row = rowbase + rf * 16 + quad * 4 + r;
                ml[(size_t)z * BT + b * SEQ + row] = make_float2(mrow[rf][r], lacc[rf][r]);
            }
        }
    }
}

// ---------------------------------------------------------------------------
// Merge NSPLIT fp16 partials. 16 threads/row, 8 cols each.
// ---------------------------------------------------------------------------
__global__ __launch_bounds__(256) void merge_kernel(
    const _Float16* __restrict__ Op,
    const float2* __restrict__ ml,
    float* __restrict__ out)
{
    int gid = blockIdx.x * 256 + threadIdx.x;
    int row = gid >> 4;
    int c8  = (gid & 15) * 8;

    float2 a[NSPLIT];
    float m = -3.0e38f;
#pragma unroll
    for (int s = 0; s < NSPLIT; s++) { a[s] = ml[(size_t)s * BT + row]; m = fmaxf(m, a[s].x); }
    float sc[NSPLIT];
    float denom = 0.f;
#pragma unroll
    for (int s = 0; s < NSPLIT; s++) { sc[s] = __expf(a[s].x - m); denom += sc[s] * a[s].y; }
    float inv = (denom > 0.f) ? (1.0f / denom) : 0.f;

    float acc[8] = {0, 0, 0, 0, 0, 0, 0, 0};
#pragma unroll
    for (int s = 0; s < NSPLIT; s++) {
        half8 o = *(const half8*)&Op[(size_t)s * BT * QD + (size_t)row * QD + c8];
#pragma unroll
        for (int e = 0; e < 8; e++) acc[e] += (float)o[e] * sc[s];
    }
    float4 lo = make_float4(acc[0] * inv, acc[1] * inv, acc[2] * inv, acc[3] * inv);
    float4 hi = make_float4(acc[4] * inv, acc[5] * inv, acc[6] * inv, acc[7] * inv);
    *(float4*)&out[(size_t)row * QD + c8] = lo;
    *(float4*)&out[(size_t)row * QD + c8 + 4] = hi;
}

extern "C" void kernel_launch(void* const* d_in, const int* in_sizes, int n_in,
                              void* d_out, int out_size, void* d_ws, size_t ws_size,
                              hipStream_t stream) {
    const float* x    = (const float*)d_in[0];
    const int*   mask = (const int*)d_in[1];
    const float* Wq   = (const float*)d_in[2];
    const float* Wk   = (const float*)d_in[3];
    const float* Wv   = (const float*)d_in[4];
    float* out = (float*)d_out;

    char* p = (char*)d_ws;
    _Float16* Wh  = (_Float16*)p; p += (size_t)3 * QD * DIM * 2;    // 768 KB
    _Float16* qb  = (_Float16*)p; p += (size_t)BT * QD * 2;         // 4 MB
    _Float16* kb  = (_Float16*)p; p += (size_t)BT * QD * 2;         // 4 MB
    _Float16* vtb = (_Float16*)p; p += (size_t)BT * QD * 2;         // 4 MB
    _Float16* Op  = (_Float16*)p; p += (size_t)NSPLIT * BT * QD * 2;// 16 MB
    float2*   ml  = (float2*)p;                                     // 512 KB

    cvt_w_kernel<<<dim3(QD * DIM / 4 / 256, 3), 256, 0, stream>>>(Wq, Wk, Wv, Wh);
    proj_kernel<<<dim3(BT / 64), 512, 0, stream>>>(x, Wh, qb, kb, vtb);
    attn_kernel<<<dim3(SEQ / 128, BATCH, NSPLIT), 256, 0, stream>>>(qb, kb, vtb, mask, Op, ml);
    merge_kernel<<<dim3(BT * 16 / 256), 256, 0, stream>>>(Op, ml, out);
}

// Round 6
// 153.934 us; speedup vs baseline: 1.1645x; 1.1645x over previous
//
#include <hip/hip_runtime.h>
#include <hip/hip_bf16.h>
#include <hip/hip_fp16.h>

typedef _Float16 half8 __attribute__((ext_vector_type(8)));
typedef _Float16 half4v __attribute__((ext_vector_type(4)));
typedef float float4v __attribute__((ext_vector_type(4)));

#define MFMA_F16(a, b, c) __builtin_amdgcn_mfma_f32_16x16x32_f16((a), (b), (c), 0, 0, 0)

// Async global->LDS DMA, 16B per lane. LDS dest = wave-uniform base + lane*16.
#define GLDS16(gp, lp) \
    __builtin_amdgcn_global_load_lds((const __attribute__((address_space(1))) unsigned int*)(gp), \
                                     (__attribute__((address_space(3))) unsigned int*)(lp), 16, 0, 0)

#define BATCH 8
#define SEQ   2048
#define DIM   1024
#define QD    128
#define BT    (BATCH * SEQ)          // 16384
#define NSPLIT 4
#define KSPAN (SEQ / NSPLIT)         // 512

// 16-lane all-lanes max reduction via DPP — pure VALU, stays off the LDS pipe.
__device__ __forceinline__ float dpp_max16(float x) {
    int v;
    v = __builtin_amdgcn_update_dpp(0, __float_as_int(x), 0xB1, 0xF, 0xF, false);  // quad_perm [1,0,3,2]
    x = fmaxf(x, __int_as_float(v));
    v = __builtin_amdgcn_update_dpp(0, __float_as_int(x), 0x4E, 0xF, 0xF, false);  // quad_perm [2,3,0,1]
    x = fmaxf(x, __int_as_float(v));
    v = __builtin_amdgcn_update_dpp(0, __float_as_int(x), 0x141, 0xF, 0xF, false); // row_half_mirror
    x = fmaxf(x, __int_as_float(v));
    v = __builtin_amdgcn_update_dpp(0, __float_as_int(x), 0x140, 0xF, 0xF, false); // row_mirror
    x = fmaxf(x, __int_as_float(v));
    return x;
}

// ---------------------------------------------------------------------------
// Weight convert (tiny, 768 KB total)
// ---------------------------------------------------------------------------
__global__ __launch_bounds__(256) void cvt_w_kernel(const float* __restrict__ Wq,
                                                    const float* __restrict__ Wk,
                                                    const float* __restrict__ Wv,
                                                    _Float16* __restrict__ Wh) {
    const float* src = (blockIdx.y == 0) ? Wq : ((blockIdx.y == 1) ? Wk : Wv);
    int i = blockIdx.x * 256 + threadIdx.x;
    float4 f = ((const float4*)src)[i];
    half4v h = {(_Float16)f.x, (_Float16)f.y, (_Float16)f.z, (_Float16)f.w};
    ((half4v*)(Wh + (size_t)blockIdx.y * QD * DIM))[i] = h;
}

// ---------------------------------------------------------------------------
// Projection v6: fused QKV, column-split for 2 blocks/CU.
// Block = 64 x-rows x 64 cols of EACH matrix (192 concatenated cols),
// blockIdx.y = column half. 512 threads, 8 waves = 2 row-halves x 4
// col-groups of 48. x once per block as f32 -> in-register cvt -> swizzled
// As (LDS); W via global_load_lds into swizzled Bs. LDS 64 KB -> 2 blocks/CU
// (grid 512): when one block sits in its barrier drain, the other block's
// waves feed the MFMA/LDS pipes — the 1-block/CU lockstep was the round-4/5
// residue. Plain __syncthreads dbuf loop (measured equal to counted vmcnt,
// race-free).
// ---------------------------------------------------------------------------
__global__ __launch_bounds__(512, 4) void proj_kernel(
    const float* __restrict__ x,         // (B*T, 1024) f32
    const _Float16* __restrict__ Wh,     // 3 x (128, 1024)
    _Float16* __restrict__ q_out,        // (B*T, 128)
    _Float16* __restrict__ k_out,        // (B*T, 128)
    _Float16* __restrict__ vt_out)       // (B, 128, T)
{
    __shared__ _Float16 As[2][64 * 64];      // 2 x 8 KB, swizzled
    __shared__ _Float16 Bs[2][192 * 64];     // 2 x 24 KB, swizzled (192 = 3x64 cols)

    const int tid  = threadIdx.x;
    const int lane = tid & 63;
    const int wave = tid >> 6;           // 0..7
    const int quad = lane >> 4;
    const int l15  = lane & 15;
    const int wr   = wave >> 2;          // 0..1 : 32-row half
    const int wcg  = wave & 3;           // 0..3 : 48-col group in 192-col space

    const int row0 = blockIdx.x * 64;
    const int ch   = blockIdx.y;         // 0..1 : 64-col half of each matrix

    // A-staging: thread -> row ar, 8-f32 col group ac8. 1 ds_write_b128 each.
    const int ar  = tid >> 3;            // 0..63
    const int ac8 = tid & 7;             // 0..7
    const float* xp = x + (size_t)(row0 + ar) * DIM + ac8 * 8;
    const int aslot = ar * 64 + ((ac8 ^ (ar & 7)) * 8);

    float4v acc[2][3];
#pragma unroll
    for (int rf = 0; rf < 2; rf++)
#pragma unroll
        for (int nf = 0; nf < 3; nf++)
            acc[rf][nf] = (float4v){0.f, 0.f, 0.f, 0.f};

    // ---- prologue: stage tile 0 into buffer 0 ----
    {
        float4 a0 = *(const float4*)(xp + 0);
        float4 a1 = *(const float4*)(xp + 4);
        // B: 192 rows x 64 halves = 1536 chunks of 16B; 3 DMA per thread.
#pragma unroll
        for (int c = 0; c < 3; c++) {
            int ci = c * 512 + tid;              // 0..1535
            int ri = ci >> 3;                    // 0..191 concatenated col
            int m  = ri >> 6;
            int wrow = ch * 64 + (ri & 63);
            int g  = (ci & 7) ^ (ri & 7);
            GLDS16(Wh + (size_t)m * QD * DIM + (size_t)wrow * DIM + g * 8, &Bs[0][ci * 8]);
        }
        half8 h;
        h[0] = (_Float16)a0.x; h[1] = (_Float16)a0.y; h[2] = (_Float16)a0.z; h[3] = (_Float16)a0.w;
        h[4] = (_Float16)a1.x; h[5] = (_Float16)a1.y; h[6] = (_Float16)a1.z; h[7] = (_Float16)a1.w;
        *(half8*)&As[0][aslot] = h;
    }
    __syncthreads();

    for (int t = 0; t < 16; t++) {
        const int cur = t & 1;
        const int nxt = cur ^ 1;

        // issue next-tile loads first (x f32 loads BEFORE W DMAs)
        float4 b0, b1;
        if (t < 15) {
            const float* xq = xp + (t + 1) * 64;
            b0 = *(const float4*)(xq + 0);
            b1 = *(const float4*)(xq + 4);
            const int kkn = (t + 1) * 64;
#pragma unroll
            for (int c = 0; c < 3; c++) {
                int ci = c * 512 + tid;
                int ri = ci >> 3;
                int m  = ri >> 6;
                int wrow = ch * 64 + (ri & 63);
                int g  = (ci & 7) ^ (ri & 7);
                GLDS16(Wh + (size_t)m * QD * DIM + (size_t)wrow * DIM + kkn + g * 8,
                       &Bs[nxt][ci * 8]);
            }
        }

        // compute current tile
        half8 af[2][2];
#pragma unroll
        for (int rf = 0; rf < 2; rf++)
#pragma unroll
            for (int kc = 0; kc < 2; kc++) {
                int r = wr * 32 + rf * 16 + l15;
                int g = (kc * 4 + quad) ^ (r & 7);
                af[rf][kc] = *(const half8*)&As[cur][r * 64 + g * 8];
            }
        half8 bf[3][2];
#pragma unroll
        for (int nf = 0; nf < 3; nf++)
#pragma unroll
            for (int kc = 0; kc < 2; kc++) {
                int r = wcg * 48 + nf * 16 + l15;      // 0..191
                int g = (kc * 4 + quad) ^ (r & 7);
                bf[nf][kc] = *(const half8*)&Bs[cur][r * 64 + g * 8];
            }
#pragma unroll
        for (int kc = 0; kc < 2; kc++)
#pragma unroll
            for (int rf = 0; rf < 2; rf++)
#pragma unroll
                for (int nf = 0; nf < 3; nf++)
                    acc[rf][nf] = MFMA_F16(af[rf][kc], bf[nf][kc], acc[rf][nf]);

        // convert + write next A tile (other buffer; safe before the barrier)
        if (t < 15) {
            half8 h;
            h[0] = (_Float16)b0.x; h[1] = (_Float16)b0.y; h[2] = (_Float16)b0.z; h[3] = (_Float16)b0.w;
            h[4] = (_Float16)b1.x; h[5] = (_Float16)b1.y; h[6] = (_Float16)b1.z; h[7] = (_Float16)b1.w;
            *(half8*)&As[nxt][aslot] = h;
            __syncthreads();
        }
    }

    // Epilogue. C layout: col = l15, row = quad*4 + reg.
#pragma unroll
    for (int rf = 0; rf < 2; rf++) {
        int grow0 = row0 + wr * 32 + rf * 16 + quad * 4;
        int b  = grow0 >> 11;
        int t0 = grow0 & 2047;
#pragma unroll
        for (int nf = 0; nf < 3; nf++) {
            int col192 = wcg * 48 + nf * 16 + l15;
            int m   = col192 >> 6;               // wave-uniform per nf
            int col = ch * 64 + (col192 & 63);   // col within the matrix
            if (m == 2) {
                half4v h;
#pragma unroll
                for (int r = 0; r < 4; r++) h[r] = (_Float16)acc[rf][nf][r];
                *(half4v*)&vt_out[((size_t)(b * QD + col)) * SEQ + t0] = h;
            } else {
                _Float16* out = (m == 0) ? q_out : k_out;
#pragma unroll
                for (int r = 0; r < 4; r++)
                    out[(size_t)(grow0 + r) * QD + col] = (_Float16)acc[rf][nf][r];
            }
        }
    }
}

// ---------------------------------------------------------------------------
// Flash attention (round-3 form: __syncthreads staging, race-free).
// Block = 128 q-rows (4 waves x 32 rows), key blocks of 64, key-split over
// blockIdx.z. K/V staged via global_load_lds into XOR-swizzled LDS; P
// round-trip also swizzled. DPP row reductions; ones-column MFMA for l;
// fp16 unnormalized partials + (m,l) for merge. Mask as float bias {0,-1e30}.
// ---------------------------------------------------------------------------
__global__ __launch_bounds__(256, 2) void attn_kernel(
    const _Float16* __restrict__ q,    // (B*T, 128)
    const _Float16* __restrict__ k,    // (B*T, 128)
    const _Float16* __restrict__ vt,   // (B, 128, T)
    const int* __restrict__ mask,      // (B*T)
    _Float16* __restrict__ Op,         // (NSPLIT, B*T, 128)
    float2* __restrict__ ml)           // (NSPLIT, B*T)
{
    __shared__ _Float16 Ks[64 * 128];      // 16 KB swizzled: keys x 128d
    __shared__ _Float16 Vs[128 * 64];      // 16 KB swizzled: 128d x keys
    __shared__ _Float16 Ps[4 * 32 * 64];   // 16 KB swizzled, wave-private slabs
    __shared__ float Msf[64];

    const int tid  = threadIdx.x;
    const int lane = tid & 63;
    const int wave = tid >> 6;
    const int quad = lane >> 4;
    const int l15  = lane & 15;

    const int b  = blockIdx.y;
    const int z  = blockIdx.z;
    const int rowbase = blockIdx.x * 128 + wave * 32;

    half8 qf[2][4];
#pragma unroll
    for (int rf = 0; rf < 2; rf++) {
        const _Float16* qrow = q + ((size_t)(b * SEQ + rowbase + rf * 16 + l15)) * QD + quad * 8;
#pragma unroll
        for (int kc = 0; kc < 4; kc++)
            qf[rf][kc] = *(const half8*)(qrow + kc * 32);
    }

    const half8 onesv = {(_Float16)1, (_Float16)1, (_Float16)1, (_Float16)1,
                         (_Float16)1, (_Float16)1, (_Float16)1, (_Float16)1};

    float4v oacc[2][8];
#pragma unroll
    for (int rf = 0; rf < 2; rf++)
#pragma unroll
        for (int n = 0; n < 8; n++)
            oacc[rf][n] = (float4v){0.f, 0.f, 0.f, 0.f};
    float4v lacc[2] = {(float4v){0.f, 0.f, 0.f, 0.f}, (float4v){0.f, 0.f, 0.f, 0.f}};
    float mrow[2][4];
#pragma unroll
    for (int rf = 0; rf < 2; rf++)
#pragma unroll
        for (int r = 0; r < 4; r++) mrow[rf][r] = -1e30f;

    _Float16* Pw = &Ps[wave * 32 * 64];

    for (int sb = z * KSPAN; sb < z * KSPAN + KSPAN; sb += 64) {
        __syncthreads();
        // K: 64 keys x 128d = 1024 chunks; 4 DMA calls/wave, swizzled dest.
#pragma unroll
        for (int c = 0; c < 4; c++) {
            int ci = wave * 256 + c * 64 + lane;
            int r  = ci >> 4;                       // key
            int gs = ci & 15;
            int g  = (gs & 8) | ((gs ^ r) & 7);     // global group for this LDS slot
            GLDS16(k + ((size_t)(b * SEQ + sb + r)) * QD + g * 8, &Ks[(wave * 256 + c * 64) * 8]);
        }
        // V^T: 128d x 64 keys = 1024 chunks; 4 DMA calls/wave.
#pragma unroll
        for (int c = 0; c < 4; c++) {
            int ci = wave * 256 + c * 64 + lane;
            int r  = ci >> 3;                       // d
            int g  = ((ci & 7) ^ r) & 7;
            GLDS16(vt + ((size_t)(b * QD + r)) * SEQ + sb + g * 8, &Vs[(wave * 256 + c * 64) * 8]);
        }
        if (tid < 64) Msf[tid] = mask[b * SEQ + sb + tid] ? 0.f : -1e30f;
        __syncthreads();

        // S = Q K^T : 32 rows x 64 keys per wave, C layout
        float4v sacc[2][4];
#pragma unroll
        for (int rf = 0; rf < 2; rf++)
#pragma unroll
            for (int j = 0; j < 4; j++)
                sacc[rf][j] = (float4v){0.f, 0.f, 0.f, 0.f};
#pragma unroll
        for (int kc = 0; kc < 4; kc++) {
            half8 kf[4];
#pragma unroll
            for (int j = 0; j < 4; j++) {
                int r  = j * 16 + l15;
                int g  = kc * 4 + quad;
                int gs = (g & 8) | ((g ^ r) & 7);
                kf[j] = *(const half8*)&Ks[r * 128 + gs * 8];
            }
#pragma unroll
            for (int rf = 0; rf < 2; rf++)
#pragma unroll
                for (int j = 0; j < 4; j++)
                    sacc[rf][j] = MFMA_F16(qf[rf][kc], kf[j], sacc[rf][j]);
        }

        // mask-bias + row-max + online-softmax scale
        float alpha[2][4];
#pragma unroll
        for (int rf = 0; rf < 2; rf++) {
            float rmax[4] = {-1e30f, -1e30f, -1e30f, -1e30f};
#pragma unroll
            for (int j = 0; j < 4; j++) {
                float bias = Msf[j * 16 + l15];
#pragma unroll
                for (int r = 0; r < 4; r++) {
                    float s = sacc[rf][j][r] + bias;
                    sacc[rf][j][r] = s;
                    rmax[r] = fmaxf(rmax[r], s);
                }
            }
#pragma unroll
            for (int r = 0; r < 4; r++) {
                float rm = dpp_max16(rmax[r]);
                float mnew = fmaxf(mrow[rf][r], rm);
                alpha[rf][r] = __expf(mrow[rf][r] - mnew);
                mrow[rf][r] = mnew;
            }
        }

        // p = exp(s - m) -> wave-private swizzled LDS (C-layout write)
#pragma unroll
        for (int rf = 0; rf < 2; rf++)
#pragma unroll
            for (int j = 0; j < 4; j++) {
                int col = j * 16 + l15;
                int gc  = col >> 3;
#pragma unroll
                for (int r = 0; r < 4; r++) {
                    int m  = rf * 16 + quad * 4 + r;
                    int gs = (gc ^ m) & 7;
                    float p = __expf(sacc[rf][j][r] - mrow[rf][r]);
                    Pw[m * 64 + gs * 8 + (col & 7)] = (_Float16)p;
                }
            }

        // rescale accumulators
#pragma unroll
        for (int rf = 0; rf < 2; rf++) {
#pragma unroll
            for (int n = 0; n < 8; n++)
#pragma unroll
                for (int r = 0; r < 4; r++)
                    oacc[rf][n][r] *= alpha[rf][r];
#pragma unroll
            for (int r = 0; r < 4; r++) lacc[rf][r] *= alpha[rf][r];
        }

        // O += P V ; l += P 1
#pragma unroll
        for (int kc = 0; kc < 2; kc++) {
            half8 pf[2];
#pragma unroll
            for (int rf = 0; rf < 2; rf++) {
                int m  = rf * 16 + l15;
                int gs = ((kc * 4 + quad) ^ m) & 7;
                pf[rf] = *(const half8*)&Pw[m * 64 + gs * 8];
            }
#pragma unroll
            for (int n = 0; n < 8; n++) {
                int r  = n * 16 + l15;
                int gs = ((kc * 4 + quad) ^ r) & 7;
                half8 vf = *(const half8*)&Vs[r * 64 + gs * 8];
#pragma unroll
                for (int rf = 0; rf < 2; rf++)
                    oacc[rf][n] = MFMA_F16(pf[rf], vf, oacc[rf][n]);
            }
#pragma unroll
            for (int rf = 0; rf < 2; rf++)
                lacc[rf] = MFMA_F16(pf[rf], onesv, lacc[rf]);
        }
    }

    // Epilogue: fp16 unnormalized partials + (m, l)
    _Float16* Oz = Op + (size_t)z * BT * QD;
#pragma unroll
    for (int rf = 0; rf < 2; rf++) {
#pragma unroll
        for (int n = 0; n < 8; n++) {
            int col = n * 16 + l15;
#pragma unroll
            for (int r = 0; r < 4; r++) {
                int row = rowbase + rf * 16 + quad * 4 + r;
                Oz[((size_t)(b * SEQ + row)) * QD + col] = (_Float16)oacc[rf][n][r];
            }
        }
        if (l15 == 0) {
#pragma unroll
            for (int r = 0; r < 4; r++) {
                int row = rowbase + rf * 16 + quad * 4 + r;
                ml[(size_t)z * BT + b * SEQ + row] = make_float2(mrow[rf][r], lacc[rf][r]);
            }
        }
    }
}

// ---------------------------------------------------------------------------
// Merge NSPLIT fp16 partials. 16 threads/row, 8 cols each.
// ---------------------------------------------------------------------------
__global__ __launch_bounds__(256) void merge_kernel(
    const _Float16* __restrict__ Op,
    const float2* __restrict__ ml,
    float* __restrict__ out)
{
    int gid = blockIdx.x * 256 + threadIdx.x;
    int row = gid >> 4;
    int c8  = (gid & 15) * 8;

    float2 a[NSPLIT];
    float m = -3.0e38f;
#pragma unroll
    for (int s = 0; s < NSPLIT; s++) { a[s] = ml[(size_t)s * BT + row]; m = fmaxf(m, a[s].x); }
    float sc[NSPLIT];
    float denom = 0.f;
#pragma unroll
    for (int s = 0; s < NSPLIT; s++) { sc[s] = __expf(a[s].x - m); denom += sc[s] * a[s].y; }
    float inv = (denom > 0.f) ? (1.0f / denom) : 0.f;

    float acc[8] = {0, 0, 0, 0, 0, 0, 0, 0};
#pragma unroll
    for (int s = 0; s < NSPLIT; s++) {
        half8 o = *(const half8*)&Op[(size_t)s * BT * QD + (size_t)row * QD + c8];
#pragma unroll
        for (int e = 0; e < 8; e++) acc[e] += (float)o[e] * sc[s];
    }
    float4 lo = make_float4(acc[0] * inv, acc[1] * inv, acc[2] * inv, acc[3] * inv);
    float4 hi = make_float4(acc[4] * inv, acc[5] * inv, acc[6] * inv, acc[7] * inv);
    *(float4*)&out[(size_t)row * QD + c8] = lo;
    *(float4*)&out[(size_t)row * QD + c8 + 4] = hi;
}

extern "C" void kernel_launch(void* const* d_in, const int* in_sizes, int n_in,
                              void* d_out, int out_size, void* d_ws, size_t ws_size,
                              hipStream_t stream) {
    const float* x    = (const float*)d_in[0];
    const int*   mask = (const int*)d_in[1];
    const float* Wq   = (const float*)d_in[2];
    const float* Wk   = (const float*)d_in[3];
    const float* Wv   = (const float*)d_in[4];
    float* out = (float*)d_out;

    char* p = (char*)d_ws;
    _Float16* Wh  = (_Float16*)p; p += (size_t)3 * QD * DIM * 2;    // 768 KB
    _Float16* qb  = (_Float16*)p; p += (size_t)BT * QD * 2;         // 4 MB
    _Float16* kb  = (_Float16*)p; p += (size_t)BT * QD * 2;         // 4 MB
    _Float16* vtb = (_Float16*)p; p += (size_t)BT * QD * 2;         // 4 MB
    _Float16* Op  = (_Float16*)p; p += (size_t)NSPLIT * BT * QD * 2;// 16 MB
    float2*   ml  = (float2*)p;                                     // 512 KB

    cvt_w_kernel<<<dim3(QD * DIM / 4 / 256, 3), 256, 0, stream>>>(Wq, Wk, Wv, Wh);
    proj_kernel<<<dim3(BT / 64, 2), 512, 0, stream>>>(x, Wh, qb, kb, vtb);
    attn_kernel<<<dim3(SEQ / 128, BATCH, NSPLIT), 256, 0, stream>>>(qb, kb, vtb, mask, Op, ml);
    merge_kernel<<<dim3(BT * 16 / 256), 256, 0, stream>>>(Op, ml, out);
}